// Round 1
// baseline (194.158 us; speedup 1.0000x reference)
//
#include <hip/hip_runtime.h>
#include <math.h>

#define BDIM 8
#define IMG 224
#define PP 16
#define GG 14
#define NN 196
#define PD 256
#define DD 128
#define DFFV 256
#define CC 1000

#define NEGINF (-INFINITY)

// ================= K1: embed + qkv layer0. grid (49,B), 384 threads ======
// Each block owns 4 rows n0..n0+3. Patches and h-rows live in LDS; h also
// written to global (needed by K2's residual). q/k/v written with pnorm folded.
__global__ __launch_bounds__(384) void embed_qkv_kernel(
    const float* __restrict__ x, const float* __restrict__ eW,
    const float* __restrict__ pos, const float* __restrict__ qW,
    const float* __restrict__ kW, const float* __restrict__ vW,
    float* __restrict__ h, float* __restrict__ qg, float* __restrict__ kg,
    float* __restrict__ vg) {
  int nt = blockIdx.x, b = blockIdx.y, n0 = nt * 4;
  __shared__ float patch[4][PD];  // 4 KB
  __shared__ float hrow[4][DD];   // 2 KB
  __shared__ float mxs[4];
  int t = threadIdx.x;
  // stage 4 patches (one per row), 256 float4 loads
  if (t < 256) {
    int p = t >> 6, r = t & 63, pi = r >> 2, pj4 = r & 3;
    int n = n0 + p, gi = n / GG, gj = n % GG;
    float4 val = *reinterpret_cast<const float4*>(
        x + (size_t)(b * IMG + gi * PP + pi) * IMG + gj * PP + pj4 * 4);
    *reinterpret_cast<float4*>(&patch[p][pi * PP + pj4 * 4]) = val;
  }
  __syncthreads();
  // embed: threads 0..255, each handles 2 rows for its d
  if (t < 256) {
    int half = t >> 7, d = t & 127;
    int p0 = half * 2, p1 = p0 + 1;
    float a0 = NEGINF, a1 = NEGINF;
    const float4* W4 = reinterpret_cast<const float4*>(eW + (size_t)d * PD);
#pragma unroll 4
    for (int j4 = 0; j4 < PD / 4; j4++) {
      float4 w = W4[j4];
      a0 = fmaxf(a0, patch[p0][j4 * 4 + 0] + w.x); a0 = fmaxf(a0, patch[p0][j4 * 4 + 1] + w.y);
      a0 = fmaxf(a0, patch[p0][j4 * 4 + 2] + w.z); a0 = fmaxf(a0, patch[p0][j4 * 4 + 3] + w.w);
      a1 = fmaxf(a1, patch[p1][j4 * 4 + 0] + w.x); a1 = fmaxf(a1, patch[p1][j4 * 4 + 1] + w.y);
      a1 = fmaxf(a1, patch[p1][j4 * 4 + 2] + w.z); a1 = fmaxf(a1, patch[p1][j4 * 4 + 3] + w.w);
    }
    float h0 = a0 + pos[(size_t)(n0 + p0) * DD + d];
    float h1v = a1 + pos[(size_t)(n0 + p1) * DD + d];
    hrow[p0][d] = h0; hrow[p1][d] = h1v;
    h[(size_t)(b * NN + n0 + p0) * DD + d] = h0;
    h[(size_t)(b * NN + n0 + p1) * DD + d] = h1v;
  }
  __syncthreads();
  // rowmax (pnorm constant) per row
  if (t < 128) {
    int r = t >> 5, l = t & 31;
    float m = fmaxf(fmaxf(hrow[r][l], hrow[r][l + 32]), fmaxf(hrow[r][l + 64], hrow[r][l + 96]));
#pragma unroll
    for (int mask = 16; mask >= 1; mask >>= 1) m = fmaxf(m, __shfl_xor(m, mask));
    if (l == 0) mxs[r] = m;
  }
  __syncthreads();
  // qkv: thread group m in {0,1,2} -> q/k/v, i = output dim
  {
    int m = t >> 7, i = t & 127;
    const float* W = (m == 0) ? qW : (m == 1 ? kW : vW);
    const float4* W4 = reinterpret_cast<const float4*>(W + (size_t)i * DD);
    float acc[4];
#pragma unroll
    for (int r = 0; r < 4; r++) acc[r] = NEGINF;
#pragma unroll 4
    for (int j4 = 0; j4 < DD / 4; j4++) {
      float4 w = W4[j4];
#pragma unroll
      for (int r = 0; r < 4; r++) {
        acc[r] = fmaxf(acc[r], hrow[r][j4 * 4 + 0] + w.x);
        acc[r] = fmaxf(acc[r], hrow[r][j4 * 4 + 1] + w.y);
        acc[r] = fmaxf(acc[r], hrow[r][j4 * 4 + 2] + w.z);
        acc[r] = fmaxf(acc[r], hrow[r][j4 * 4 + 3] + w.w);
      }
    }
    float* dst = (m == 0) ? qg : (m == 1 ? kg : vg);
#pragma unroll
    for (int r = 0; r < 4; r++)
      dst[(size_t)(b * NN + n0 + r) * DD + i] = acc[r] - mxs[r];
  }
}

// ========== K2/K3: attn + ffn1 + ffn2 (+ optional next-layer qkv) =========
// grid (49,B), 384 threads. hrow and h1 stay in LDS for the whole layer.
// Cross-block data: reads k/v of all rows (pre-written by previous kernel),
// writes its own h rows at the end; optional qkv writes q in-place (only the
// owning block ever reads its own q rows) and k2/v2 to fresh buffers.
__global__ __launch_bounds__(384) void layer_kernel(
    const float* __restrict__ qg, const float* __restrict__ kg,
    const float* __restrict__ vg, float* __restrict__ h,
    const float* __restrict__ f1W, const float* __restrict__ f2W,
    const float* __restrict__ tau, const float* __restrict__ qWn,
    const float* __restrict__ kWn, const float* __restrict__ vWn,
    float* __restrict__ qo, float* __restrict__ ko, float* __restrict__ vo) {
  int nt = blockIdx.x, b = blockIdx.y, i0 = nt * 4;
  __shared__ float qs[4][DD];        // 2 KB
  __shared__ float hrow[4][DD];      // 2 KB (persistent x across the layer)
  __shared__ float sc[4][NN];        // 3.1 KB
  __shared__ float h1s[4][DFFV];     // 4 KB
  __shared__ float scratch[12 * 4 * DD];  // 24 KB (ored / ffn2-part alias)
  __shared__ float red[2][4];
  __shared__ float mxs[4];
  int t = threadIdx.x;
  // ---- stage qs (own q rows) and hrow (own h rows) ----
  if (t < 128) {
    float4 val = reinterpret_cast<const float4*>(qg + (size_t)(b * NN + i0) * DD)[t];
    *reinterpret_cast<float4*>(&qs[0][0] + t * 4) = val;
  } else if (t < 256) {
    int tt = t - 128;
    float4 val = reinterpret_cast<const float4*>(h + (size_t)(b * NN + i0) * DD)[tt];
    *reinterpret_cast<float4*>(&hrow[0][0] + tt * 4) = val;
  }
  __syncthreads();
  // ---- scores: thread t = key index j ----
  if (t < NN) {
    const float4* k4 = reinterpret_cast<const float4*>(kg + (size_t)(b * NN + t) * DD);
    float s0 = NEGINF, s1 = NEGINF, s2 = NEGINF, s3 = NEGINF;
#pragma unroll 4
    for (int d4 = 0; d4 < DD / 4; d4++) {
      float4 kv = k4[d4];
      s0 = fmaxf(s0, qs[0][d4 * 4 + 0] + kv.x); s0 = fmaxf(s0, qs[0][d4 * 4 + 1] + kv.y);
      s0 = fmaxf(s0, qs[0][d4 * 4 + 2] + kv.z); s0 = fmaxf(s0, qs[0][d4 * 4 + 3] + kv.w);
      s1 = fmaxf(s1, qs[1][d4 * 4 + 0] + kv.x); s1 = fmaxf(s1, qs[1][d4 * 4 + 1] + kv.y);
      s1 = fmaxf(s1, qs[1][d4 * 4 + 2] + kv.z); s1 = fmaxf(s1, qs[1][d4 * 4 + 3] + kv.w);
      s2 = fmaxf(s2, qs[2][d4 * 4 + 0] + kv.x); s2 = fmaxf(s2, qs[2][d4 * 4 + 1] + kv.y);
      s2 = fmaxf(s2, qs[2][d4 * 4 + 2] + kv.z); s2 = fmaxf(s2, qs[2][d4 * 4 + 3] + kv.w);
      s3 = fmaxf(s3, qs[3][d4 * 4 + 0] + kv.x); s3 = fmaxf(s3, qs[3][d4 * 4 + 1] + kv.y);
      s3 = fmaxf(s3, qs[3][d4 * 4 + 2] + kv.z); s3 = fmaxf(s3, qs[3][d4 * 4 + 3] + kv.w);
    }
    sc[0][t] = s0; sc[1][t] = s1; sc[2][t] = s2; sc[3][t] = s3;
  }
  __syncthreads();
  // ---- PV: 12 j-groups x 32 d4-slots over all 384 threads ----
  {
    int d4 = t & 31, jg = t >> 5;
    float4 o0 = {NEGINF, NEGINF, NEGINF, NEGINF};
    float4 o1 = o0, o2 = o0, o3 = o0;
#pragma unroll 4
    for (int j = jg; j < NN; j += 12) {
      float4 vv = *reinterpret_cast<const float4*>(vg + (size_t)(b * NN + j) * DD + d4 * 4);
      float c0 = sc[0][j], c1 = sc[1][j], c2 = sc[2][j], c3 = sc[3][j];
      o0.x = fmaxf(o0.x, c0 + vv.x); o0.y = fmaxf(o0.y, c0 + vv.y);
      o0.z = fmaxf(o0.z, c0 + vv.z); o0.w = fmaxf(o0.w, c0 + vv.w);
      o1.x = fmaxf(o1.x, c1 + vv.x); o1.y = fmaxf(o1.y, c1 + vv.y);
      o1.z = fmaxf(o1.z, c1 + vv.z); o1.w = fmaxf(o1.w, c1 + vv.w);
      o2.x = fmaxf(o2.x, c2 + vv.x); o2.y = fmaxf(o2.y, c2 + vv.y);
      o2.z = fmaxf(o2.z, c2 + vv.z); o2.w = fmaxf(o2.w, c2 + vv.w);
      o3.x = fmaxf(o3.x, c3 + vv.x); o3.y = fmaxf(o3.y, c3 + vv.y);
      o3.z = fmaxf(o3.z, c3 + vv.z); o3.w = fmaxf(o3.w, c3 + vv.w);
    }
    float* ored = scratch;  // [12][4][DD]
    *reinterpret_cast<float4*>(&ored[((jg * 4 + 0) << 7) + d4 * 4]) = o0;
    *reinterpret_cast<float4*>(&ored[((jg * 4 + 1) << 7) + d4 * 4]) = o1;
    *reinterpret_cast<float4*>(&ored[((jg * 4 + 2) << 7) + d4 * 4]) = o2;
    *reinterpret_cast<float4*>(&ored[((jg * 4 + 3) << 7) + d4 * 4]) = o3;
  }
  __syncthreads();
  // ---- combine 12 groups, pnorm over d, tropical residual into hrow ----
  float oacc[4];
  if (t < 128) {
    int lane = t & 63, wv = t >> 6;
#pragma unroll
    for (int r = 0; r < 4; r++) {
      float m = scratch[(r << 7) + t];
#pragma unroll
      for (int g = 1; g < 12; g++) m = fmaxf(m, scratch[((g * 4 + r) << 7) + t]);
      oacc[r] = m;
      float mv = m;
#pragma unroll
      for (int mask = 32; mask >= 1; mask >>= 1) mv = fmaxf(mv, __shfl_xor(mv, mask));
      if (lane == 0) red[wv][r] = mv;
    }
  }
  __syncthreads();
  if (t < 128) {
#pragma unroll
    for (int r = 0; r < 4; r++) {
      float omax = fmaxf(red[0][r], red[1][r]);
      hrow[r][t] = fmaxf(hrow[r][t], oacc[r] - omax);
    }
  }
  __syncthreads();
  // ---- ffn1: rowmax then h1 = max(trop_mm(xn,f1W), tau), all in LDS ----
  if (t < 128) {
    int r = t >> 5, l = t & 31;
    float m = fmaxf(fmaxf(hrow[r][l], hrow[r][l + 32]), fmaxf(hrow[r][l + 64], hrow[r][l + 96]));
#pragma unroll
    for (int mask = 16; mask >= 1; mask >>= 1) m = fmaxf(m, __shfl_xor(m, mask));
    if (l == 0) mxs[r] = m;
  }
  __syncthreads();
  if (t < 256) {
    float tv = tau[0];
    const float4* W4 = reinterpret_cast<const float4*>(f1W + (size_t)t * DD);
    float acc[4];
#pragma unroll
    for (int r = 0; r < 4; r++) acc[r] = NEGINF;
#pragma unroll 4
    for (int j4 = 0; j4 < DD / 4; j4++) {
      float4 w = W4[j4];
#pragma unroll
      for (int r = 0; r < 4; r++) {
        acc[r] = fmaxf(acc[r], hrow[r][j4 * 4 + 0] + w.x);
        acc[r] = fmaxf(acc[r], hrow[r][j4 * 4 + 1] + w.y);
        acc[r] = fmaxf(acc[r], hrow[r][j4 * 4 + 2] + w.z);
        acc[r] = fmaxf(acc[r], hrow[r][j4 * 4 + 3] + w.w);
      }
    }
#pragma unroll
    for (int r = 0; r < 4; r++) h1s[r][t] = fmaxf(acc[r] - mxs[r], tv);
  }
  __syncthreads();
  // ---- ffn2: two DFF-halves, partials in scratch, pnorm + residual ----
  if (t < 256) {
    int i = t & 127, jh = t >> 7;
    const float4* W4 = reinterpret_cast<const float4*>(f2W + (size_t)i * DFFV) + jh * 32;
    float acc[4];
#pragma unroll
    for (int r = 0; r < 4; r++) acc[r] = NEGINF;
#pragma unroll 4
    for (int j4 = 0; j4 < 32; j4++) {
      float4 w = W4[j4];
      int jb = jh * 128 + j4 * 4;
#pragma unroll
      for (int r = 0; r < 4; r++) {
        acc[r] = fmaxf(acc[r], h1s[r][jb + 0] + w.x);
        acc[r] = fmaxf(acc[r], h1s[r][jb + 1] + w.y);
        acc[r] = fmaxf(acc[r], h1s[r][jb + 2] + w.z);
        acc[r] = fmaxf(acc[r], h1s[r][jb + 3] + w.w);
      }
    }
    float* part = scratch;  // [2][4][DD]
#pragma unroll
    for (int r = 0; r < 4; r++) part[((jh * 4 + r) << 7) + i] = acc[r];
  }
  __syncthreads();
  float fm[4];
  if (t < 128) {
    int lane = t & 63, wv = t >> 6;
#pragma unroll
    for (int r = 0; r < 4; r++) {
      fm[r] = fmaxf(scratch[(r << 7) + t], scratch[((4 + r) << 7) + t]);
      float mv = fm[r];
#pragma unroll
      for (int mask = 32; mask >= 1; mask >>= 1) mv = fmaxf(mv, __shfl_xor(mv, mask));
      if (lane == 0) red[wv][r] = mv;
    }
  }
  __syncthreads();
  if (t < 128) {
#pragma unroll
    for (int r = 0; r < 4; r++) {
      float omax = fmaxf(red[0][r], red[1][r]);
      float nh = fmaxf(hrow[r][t], fm[r] - omax);
      hrow[r][t] = nh;
      h[(size_t)(b * NN + i0 + r) * DD + t] = nh;  // hand off to next kernel
    }
  }
  __syncthreads();
  // ---- optional next-layer qkv straight from LDS hrow ----
  if (qWn != nullptr) {
    if (t < 128) {
      int r = t >> 5, l = t & 31;
      float m = fmaxf(fmaxf(hrow[r][l], hrow[r][l + 32]), fmaxf(hrow[r][l + 64], hrow[r][l + 96]));
#pragma unroll
      for (int mask = 16; mask >= 1; mask >>= 1) m = fmaxf(m, __shfl_xor(m, mask));
      if (l == 0) mxs[r] = m;
    }
    __syncthreads();
    int m = t >> 7, i = t & 127;
    const float* W = (m == 0) ? qWn : (m == 1 ? kWn : vWn);
    const float4* W4 = reinterpret_cast<const float4*>(W + (size_t)i * DD);
    float acc[4];
#pragma unroll
    for (int r = 0; r < 4; r++) acc[r] = NEGINF;
#pragma unroll 4
    for (int j4 = 0; j4 < DD / 4; j4++) {
      float4 w = W4[j4];
#pragma unroll
      for (int r = 0; r < 4; r++) {
        acc[r] = fmaxf(acc[r], hrow[r][j4 * 4 + 0] + w.x);
        acc[r] = fmaxf(acc[r], hrow[r][j4 * 4 + 1] + w.y);
        acc[r] = fmaxf(acc[r], hrow[r][j4 * 4 + 2] + w.z);
        acc[r] = fmaxf(acc[r], hrow[r][j4 * 4 + 3] + w.w);
      }
    }
    float* dst = (m == 0) ? qo : (m == 1 ? ko : vo);
#pragma unroll
    for (int r = 0; r < 4; r++)
      dst[(size_t)(b * NN + i0 + r) * DD + i] = acc[r] - mxs[r];
  }
}

// ---------------- head: grid (32, B), 256 threads (unchanged) -------------
__global__ void head_kernel(const float* __restrict__ h, const float* __restrict__ hW,
                            const float* __restrict__ lscale, float* __restrict__ out) {
  int cc = blockIdx.x, b = blockIdx.y;
  __shared__ float plds[8][DD];
  __shared__ float pooled[DD];
  __shared__ float gred[8][32];
  int t = threadIdx.x;
  {
    int d4 = t & 31, ng = t >> 5;
    float4 pm = {NEGINF, NEGINF, NEGINF, NEGINF};
#pragma unroll 4
    for (int n = ng; n < NN; n += 8) {
      float4 hv = *reinterpret_cast<const float4*>(h + (size_t)(b * NN + n) * DD + d4 * 4);
      pm.x = fmaxf(pm.x, hv.x); pm.y = fmaxf(pm.y, hv.y);
      pm.z = fmaxf(pm.z, hv.z); pm.w = fmaxf(pm.w, hv.w);
    }
    *reinterpret_cast<float4*>(&plds[ng][d4 * 4]) = pm;
  }
  __syncthreads();
  if (t < DD) {
    float m = plds[0][t];
#pragma unroll
    for (int g = 1; g < 8; g++) m = fmaxf(m, plds[g][t]);
    pooled[t] = m;
  }
  __syncthreads();
  int cl = t & 31, ds = t >> 5;
  int c = cc * 32 + cl;
  float acc = NEGINF;
  if (c < CC) {
    const float4* W4 = reinterpret_cast<const float4*>(hW + (size_t)c * DD) + ds * 4;
#pragma unroll
    for (int kk = 0; kk < 4; kk++) {
      float4 w = W4[kk];
      int db = ds * 16 + kk * 4;
      acc = fmaxf(acc, pooled[db + 0] + w.x);
      acc = fmaxf(acc, pooled[db + 1] + w.y);
      acc = fmaxf(acc, pooled[db + 2] + w.z);
      acc = fmaxf(acc, pooled[db + 3] + w.w);
    }
  }
  gred[ds][cl] = acc;
  __syncthreads();
  if (t < 32) {
    int c2 = cc * 32 + t;
    if (c2 < CC) {
      float m = gred[0][t];
#pragma unroll
      for (int g = 1; g < 8; g++) m = fmaxf(m, gred[g][t]);
      out[(size_t)b * CC + c2] = m * lscale[0];
    }
  }
}

extern "C" void kernel_launch(void* const* d_in, const int* in_sizes, int n_in,
                              void* d_out, int out_size, void* d_ws, size_t ws_size,
                              hipStream_t stream) {
  const float* x = (const float*)d_in[0];
  const float* embed_W = (const float*)d_in[1];
  const float* pos = (const float*)d_in[2];
  const float* qW[2] = {(const float*)d_in[3], (const float*)d_in[9]};
  const float* kW[2] = {(const float*)d_in[4], (const float*)d_in[10]};
  const float* vW[2] = {(const float*)d_in[5], (const float*)d_in[11]};
  const float* f1W[2] = {(const float*)d_in[6], (const float*)d_in[12]};
  const float* f2W[2] = {(const float*)d_in[7], (const float*)d_in[13]};
  const float* tau[2] = {(const float*)d_in[8], (const float*)d_in[14]};
  const float* headW = (const float*)d_in[15];
  const float* lscale = (const float*)d_in[16];
  float* out = (float*)d_out;

  float* ws = (float*)d_ws;
  size_t o = 0;
  float* h = ws + o; o += (size_t)BDIM * NN * DD;
  float* qb = ws + o; o += (size_t)BDIM * NN * DD;
  float* kb = ws + o; o += (size_t)BDIM * NN * DD;
  float* vb = ws + o; o += (size_t)BDIM * NN * DD;
  float* k2 = ws + o; o += (size_t)BDIM * NN * DD;
  float* v2 = ws + o; o += (size_t)BDIM * NN * DD;

  // K1: embed + qkv(L0)
  embed_qkv_kernel<<<dim3(49, BDIM), 384, 0, stream>>>(
      x, embed_W, pos, qW[0], kW[0], vW[0], h, qb, kb, vb);
  // K2: attn(L0)+ffn(L0)+qkv(L1); q overwritten in place, k/v double-buffered
  layer_kernel<<<dim3(49, BDIM), 384, 0, stream>>>(
      qb, kb, vb, h, f1W[0], f2W[0], tau[0], qW[1], kW[1], vW[1], qb, k2, v2);
  // K3: attn(L1)+ffn(L1), no next qkv
  layer_kernel<<<dim3(49, BDIM), 384, 0, stream>>>(
      qb, k2, v2, h, f1W[1], f2W[1], tau[1], nullptr, nullptr, nullptr,
      nullptr, nullptr, nullptr);
  // K4: head
  head_kernel<<<dim3(32, BDIM), 256, 0, stream>>>(h, headW, lscale, out);
}